// Round 4
// baseline (143.935 us; speedup 1.0000x reference)
//
#include <hip/hip_runtime.h>

#define NA 16
#define DD 513
#define ALPHA 0.1f
#define EPSV 1e-7f
#define RPW 16            // rows per wave
#define GRID 2048         // 2048 blocks * 4 waves * 16 rows = 131072

typedef __fp16 h2 __attribute__((ext_vector_type(2)));
typedef unsigned int u32;

union H2U { h2 h; u32 u; };

static __device__ __forceinline__ u32 pkrtz(float lo, float hi) {
    H2U t; t.h = __builtin_amdgcn_cvt_pkrtz(lo, hi); return t.u;
}
static __device__ __forceinline__ h2 asH2(u32 w) { H2U t; t.u = w; return t.h; }

static __device__ __forceinline__ float fdot2(u32 a, u32 b, float c) {
#if __has_builtin(__builtin_amdgcn_fdot2)
    return __builtin_amdgcn_fdot2(asH2(a), asH2(b), c, false);
#else
    h2 ha = asH2(a), hb = asH2(b);
    c = fmaf((float)ha.x, (float)hb.x, c);
    return fmaf((float)ha.y, (float)hb.y, c);
#endif
}

// 4-byte-aligned float4 for (mis)aligned row slices
struct __attribute__((packed, aligned(4))) F4 { float a, b, c, d; };

// reduce 64 lanes x 16 values -> every lane holds full sum for anchor
// aidx(lane) = 8*b0 + 4*b1 + 2*b2 + b3  (bits of lane)
#define RSTEP(m, half)                                              \
    _Pragma("unroll")                                               \
    for (int i = 0; i < half; ++i) {                                \
        const bool up = (lane & m) != 0;                            \
        float snd = up ? v[i] : v[half + i];                        \
        float kp  = up ? v[half + i] : v[i];                        \
        v[i] = kp + __shfl_xor(snd, m);                             \
    }

static __device__ __forceinline__ float reduce16(float v[16], int lane) {
    RSTEP(1, 8)
    RSTEP(2, 4)
    RSTEP(4, 2)
    RSTEP(8, 1)
    float S = v[0];
    S += __shfl_xor(S, 16);
    S += __shfl_xor(S, 32);
    return S;
}

__global__ __launch_bounds__(256, 4)
void hfield_kernel(const float* __restrict__ x,
                   const float* __restrict__ anc,
                   float* __restrict__ out) {
    __shared__ u32 ah[NA][256];   // packed f16 pairs of spatial anchor parts

    const int tid = threadIdx.x, lane = tid & 63, wid = tid >> 6;

    for (int i = tid; i < NA * 256; i += 256) {
        const int a = i >> 8, w = i & 255;
        ah[a][w] = pkrtz(anc[a * DD + 1 + 2 * w], anc[a * DD + 2 + 2 * w]);
    }
    __syncthreads();

    const int aidx = ((lane & 1) << 3) | (((lane >> 1) & 1) << 2) |
                     (((lane >> 2) & 1) << 1) | ((lane >> 3) & 1);

    // af0 for anchor aidx: sqrt(1 + sum(sp^2))
    float af0;
    {
        float v[16];
#pragma unroll
        for (int a = 0; a < NA; ++a) {
            const uint4 w = *reinterpret_cast<const uint4*>(&ah[a][4 * lane]);
            float s = fdot2(w.x, w.x, 0.f);
            s = fdot2(w.y, w.y, s);
            s = fdot2(w.z, w.z, s);
            v[a] = fdot2(w.w, w.w, s);
        }
        af0 = sqrtf(1.0f + reduce16(v, lane));
    }

    const int gw = blockIdx.x * 4 + wid;
    const float* rbase = x + (size_t)gw * RPW * DD;
    float*       obase = out + (size_t)gw * RPW * DD;

    // pipeline: rows it (xa), it+1 (xb), prefetch it+2 (xn)
    float xa[8], xb[8];
    float x0a, x0b;
    {
        const float* p = rbase + 1 + 8 * lane;
        F4 lo = *(const F4*)p, hi = *(const F4*)(p + 4);
        xa[0] = lo.a; xa[1] = lo.b; xa[2] = lo.c; xa[3] = lo.d;
        xa[4] = hi.a; xa[5] = hi.b; xa[6] = hi.c; xa[7] = hi.d;
        x0a = rbase[0];
        const float* q = rbase + DD + 1 + 8 * lane;
        F4 lo2 = *(const F4*)q, hi2 = *(const F4*)(q + 4);
        xb[0] = lo2.a; xb[1] = lo2.b; xb[2] = lo2.c; xb[3] = lo2.d;
        xb[4] = hi2.a; xb[5] = hi2.b; xb[6] = hi2.c; xb[7] = hi2.d;
        x0b = rbase[DD];
    }

#pragma unroll 1
    for (int it = 0; it < RPW; ++it) {
        float xn[8] = {0, 0, 0, 0, 0, 0, 0, 0};
        float x0n = 0.f;
        if (it + 2 < RPW) {
            const float* p = rbase + (size_t)(it + 2) * DD;
            F4 lo = *(const F4*)(p + 1 + 8 * lane);
            F4 hi = *(const F4*)(p + 5 + 8 * lane);
            xn[0] = lo.a; xn[1] = lo.b; xn[2] = lo.c; xn[3] = lo.d;
            xn[4] = hi.a; xn[5] = hi.b; xn[6] = hi.c; xn[7] = hi.d;
            x0n = p[0];
        }

        const u32 xp0 = pkrtz(xa[0], xa[1]);
        const u32 xp1 = pkrtz(xa[2], xa[3]);
        const u32 xp2 = pkrtz(xa[4], xa[5]);
        const u32 xp3 = pkrtz(xa[6], xa[7]);

        float v[16];
#pragma unroll
        for (int a = 0; a < NA; ++a) {
            const uint4 w = *reinterpret_cast<const uint4*>(&ah[a][4 * lane]);
            float s = fdot2(w.x, xp0, 0.f);
            s = fdot2(w.y, xp1, s);
            s = fdot2(w.z, xp2, s);
            v[a] = fdot2(w.w, xp3, s);
        }
        const float S = reduce16(v, lane);

        // theta for anchor aidx, clipped
        float tc = fmaxf(fmaf(x0a, af0, -S), 1.0f + 1e-7f);
        int idx = aidx;
#pragma unroll
        for (int m = 1; m <= 8; m <<= 1) {
            float vo = __shfl_xor(tc, m);
            int   io = __shfl_xor(idx, m);
            bool take = (vo < tc) || (vo == tc && io < idx);
            tc  = take ? vo : tc;
            idx = take ? io : idx;
        }
        const int bi = __builtin_amdgcn_readfirstlane(idx);

        // scalar epilogue (wave-uniform)
        const float s2   = tc * tc - 1.0f;
        const float rr   = sqrtf(s2);
        const float ach  = __logf(tc + rr);           // arccosh
        const float coef = ach / rr;
        const float vn   = sqrtf(fmaxf(ALPHA * ALPHA * ach * ach, EPSV));
        const float e    = __expf(vn);
        const float ei   = 1.0f / e;
        const float ch   = 0.5f * (e + ei);
        const float sh   = 0.5f * (e - ei);
        const float c2   = ALPHA * coef * (sh / vn);
        const float c1   = fmaf(-c2, tc, ch);

        // y slice for winning anchor from LDS
        const uint4 wy = *reinterpret_cast<const uint4*>(&ah[bi][4 * lane]);
        float yv[8];
        { h2 t = asH2(wy.x); yv[0] = (float)t.x; yv[1] = (float)t.y; }
        { h2 t = asH2(wy.y); yv[2] = (float)t.x; yv[3] = (float)t.y; }
        { h2 t = asH2(wy.z); yv[4] = (float)t.x; yv[5] = (float)t.y; }
        { h2 t = asH2(wy.w); yv[6] = (float)t.x; yv[7] = (float)t.y; }

        float* op = obase + (size_t)it * DD;
        float* sp = op + 1 + 8 * lane;
#pragma unroll
        for (int j = 0; j < 8; ++j)
            __builtin_nontemporal_store(fmaf(c2, yv[j], c1 * xa[j]), &sp[j]);

        const int lsrc = ((bi >> 3) & 1) | (((bi >> 2) & 1) << 1) |
                         (((bi >> 1) & 1) << 2) | ((bi & 1) << 3);
        const float y0 = __shfl(af0, lsrc);
        if (lane == 0)
            __builtin_nontemporal_store(fmaf(c2, y0, c1 * x0a), op);

        // rotate pipeline
#pragma unroll
        for (int j = 0; j < 8; ++j) { xa[j] = xb[j]; xb[j] = xn[j]; }
        x0a = x0b; x0b = x0n;
    }
}

extern "C" void kernel_launch(void* const* d_in, const int* in_sizes, int n_in,
                              void* d_out, int out_size, void* d_ws, size_t ws_size,
                              hipStream_t stream) {
    const float* x   = (const float*)d_in[0];
    const float* anc = (const float*)d_in[1];
    float* out       = (float*)d_out;
    hipLaunchKernelGGL(hfield_kernel, dim3(GRID), dim3(256), 0, stream, x, anc, out);
}

// Round 5
// 124.691 us; speedup vs baseline: 1.1543x; 1.1543x over previous
//
#include <hip/hip_runtime.h>

#define NA 16
#define DD 513
#define ALPHA 0.1f
#define EPSV 1e-7f
#define RPW 16            // rows per wave
#define GRID 2048         // 2048 blocks * 4 waves * 16 rows = 131072

typedef __fp16 h2 __attribute__((ext_vector_type(2)));
typedef unsigned int u32;

union H2U { h2 h; u32 u; };

static __device__ __forceinline__ u32 pkrtz(float lo, float hi) {
    H2U t; t.h = __builtin_amdgcn_cvt_pkrtz(lo, hi); return t.u;
}
static __device__ __forceinline__ h2 asH2(u32 w) { H2U t; t.u = w; return t.h; }

static __device__ __forceinline__ float fdot2(u32 a, u32 b, float c) {
#if __has_builtin(__builtin_amdgcn_fdot2)
    return __builtin_amdgcn_fdot2(asH2(a), asH2(b), c, false);
#else
    h2 ha = asH2(a), hb = asH2(b);
    c = fmaf((float)ha.x, (float)hb.x, c);
    return fmaf((float)ha.y, (float)hb.y, c);
#endif
}

// reduce 64 lanes x 16 values -> every lane holds full sum for anchor
// aidx(lane) = bitrev4(lane & 15)
#define RSTEP(m, half)                                              \
    _Pragma("unroll")                                               \
    for (int i = 0; i < half; ++i) {                                \
        const bool up = (lane & m) != 0;                            \
        float snd = up ? v[i] : v[half + i];                        \
        float kp  = up ? v[half + i] : v[i];                        \
        v[i] = kp + __shfl_xor(snd, m);                             \
    }

static __device__ __forceinline__ float reduce16(float v[16], int lane) {
    RSTEP(1, 8)
    RSTEP(2, 4)
    RSTEP(4, 2)
    RSTEP(8, 1)
    float S = v[0];
    S += __shfl_xor(S, 16);
    S += __shfl_xor(S, 32);
    return S;
}

__global__ __launch_bounds__(256, 4)
void hfield_kernel(const float* __restrict__ x,
                   const float* __restrict__ anc,
                   float* __restrict__ out) {
    // ah[a][l][k] packs (anc[a][1+l+128k], anc[a][1+l+64+128k]) as f16x2
    __shared__ u32 ah[NA][64][4];

    const int tid = threadIdx.x, lane = tid & 63, wid = tid >> 6;

    for (int i = tid; i < NA * 256; i += 256) {
        const int a = i >> 8, rem = i & 255, l = rem >> 2, k = rem & 3;
        ah[a][l][k] = pkrtz(anc[a * DD + 1 + l + 128 * k],
                            anc[a * DD + 1 + l + 64 + 128 * k]);
    }
    __syncthreads();

    const int aidx = ((lane & 1) << 3) | (((lane >> 1) & 1) << 2) |
                     (((lane >> 2) & 1) << 1) | ((lane >> 3) & 1);

    // af0 for anchor aidx: sqrt(1 + sum(sp^2))
    float af0;
    {
        float v[16];
#pragma unroll
        for (int a = 0; a < NA; ++a) {
            const uint4 w = *reinterpret_cast<const uint4*>(&ah[a][lane][0]);
            float s = fdot2(w.x, w.x, 0.f);
            s = fdot2(w.y, w.y, s);
            s = fdot2(w.z, w.z, s);
            v[a] = fdot2(w.w, w.w, s);
        }
        af0 = sqrtf(1.0f + reduce16(v, lane));
    }

    const int gw = blockIdx.x * 4 + wid;
    const float* rbase = x + (size_t)gw * RPW * DD;
    float*       obase = out + (size_t)gw * RPW * DD;

    // register pipeline: row it (xa), it+1 (xb), prefetch it+2 (xn)
    // interleaved slices: xc[j] = row[1 + lane + 64j]  (coalesced 256B/instr)
    float xa[8], xb[8];
    float x0a, x0b;
    {
        const float* p = rbase + 1 + lane;
#pragma unroll
        for (int j = 0; j < 8; ++j) xa[j] = p[64 * j];
        x0a = rbase[0];
        const float* q = rbase + DD + 1 + lane;
#pragma unroll
        for (int j = 0; j < 8; ++j) xb[j] = q[64 * j];
        x0b = rbase[DD];
    }

#pragma unroll 1
    for (int it = 0; it < RPW; ++it) {
        float xn[8] = {0, 0, 0, 0, 0, 0, 0, 0};
        float x0n = 0.f;
        if (it + 2 < RPW) {
            const float* p = rbase + (size_t)(it + 2) * DD;
            const float* ps = p + 1 + lane;
#pragma unroll
            for (int j = 0; j < 8; ++j) xn[j] = ps[64 * j];
            x0n = p[0];
        }

        // pack current row into f16 pairs along j: pair k = (j=2k, j=2k+1)
        const u32 xp0 = pkrtz(xa[0], xa[1]);
        const u32 xp1 = pkrtz(xa[2], xa[3]);
        const u32 xp2 = pkrtz(xa[4], xa[5]);
        const u32 xp3 = pkrtz(xa[6], xa[7]);

        float v[16];
#pragma unroll
        for (int a = 0; a < NA; ++a) {
            const uint4 w = *reinterpret_cast<const uint4*>(&ah[a][lane][0]);
            float s = fdot2(w.x, xp0, 0.f);
            s = fdot2(w.y, xp1, s);
            s = fdot2(w.z, xp2, s);
            v[a] = fdot2(w.w, xp3, s);
        }
        const float S = reduce16(v, lane);

        // theta for anchor aidx, clipped
        float tc = fmaxf(fmaf(x0a, af0, -S), 1.0f + 1e-7f);
        int idx = aidx;
#pragma unroll
        for (int m = 1; m <= 8; m <<= 1) {
            float vo = __shfl_xor(tc, m);
            int   io = __shfl_xor(idx, m);
            bool take = (vo < tc) || (vo == tc && io < idx);
            tc  = take ? vo : tc;
            idx = take ? io : idx;
        }
        const int bi = __builtin_amdgcn_readfirstlane(idx);

        // scalar epilogue (wave-uniform)
        const float s2   = tc * tc - 1.0f;
        const float rr   = sqrtf(s2);
        const float ach  = __logf(tc + rr);           // arccosh
        const float coef = ach / rr;
        const float vn   = sqrtf(fmaxf(ALPHA * ALPHA * ach * ach, EPSV));
        const float e    = __expf(vn);
        const float ei   = 1.0f / e;
        const float ch   = 0.5f * (e + ei);
        const float sh   = 0.5f * (e - ei);
        const float c2   = ALPHA * coef * (sh / vn);
        const float c1   = fmaf(-c2, tc, ch);

        // y slice for winning anchor (interleaved: yv[2k], yv[2k+1] from pair k)
        const uint4 wy = *reinterpret_cast<const uint4*>(&ah[bi][lane][0]);
        float yv[8];
        { h2 t = asH2(wy.x); yv[0] = (float)t.x; yv[1] = (float)t.y; }
        { h2 t = asH2(wy.y); yv[2] = (float)t.x; yv[3] = (float)t.y; }
        { h2 t = asH2(wy.z); yv[4] = (float)t.x; yv[5] = (float)t.y; }
        { h2 t = asH2(wy.w); yv[6] = (float)t.x; yv[7] = (float)t.y; }

        float* op = obase + (size_t)it * DD;
        float* sp = op + 1 + lane;
#pragma unroll
        for (int j = 0; j < 8; ++j)
            __builtin_nontemporal_store(fmaf(c2, yv[j], c1 * xa[j]), &sp[64 * j]);

        const int lsrc = ((bi >> 3) & 1) | (((bi >> 2) & 1) << 1) |
                         (((bi >> 1) & 1) << 2) | ((bi & 1) << 3);
        const float y0 = __shfl(af0, lsrc);
        if (lane == 0)
            __builtin_nontemporal_store(fmaf(c2, y0, c1 * x0a), op);

        // rotate pipeline
#pragma unroll
        for (int j = 0; j < 8; ++j) { xa[j] = xb[j]; xb[j] = xn[j]; }
        x0a = x0b; x0b = x0n;
    }
}

extern "C" void kernel_launch(void* const* d_in, const int* in_sizes, int n_in,
                              void* d_out, int out_size, void* d_ws, size_t ws_size,
                              hipStream_t stream) {
    const float* x   = (const float*)d_in[0];
    const float* anc = (const float*)d_in[1];
    float* out       = (float*)d_out;
    hipLaunchKernelGGL(hfield_kernel, dim3(GRID), dim3(256), 0, stream, x, anc, out);
}